// Round 9
// baseline (597.670 us; speedup 1.0000x reference)
//
#include <hip/hip_runtime.h>

#define EPS 1e-15f

__device__ __forceinline__ float rl(float v, int l) {
    return __int_as_float(__builtin_amdgcn_readlane(__float_as_int(v), l));
}

// ---------- in-degree histogram (int counts) ----------
__global__ void k_hist(const int* __restrict__ ei, int E, int* __restrict__ counts) {
    int e = blockIdx.x * blockDim.x + threadIdx.x;
    if (e < E) atomicAdd(&counts[ei[E + e]], 1);
}

// ---------- parallel scan, phase 1: per-block sums (1024 elems/block) ----------
__global__ __launch_bounds__(1024) void k_scan1(const int* __restrict__ counts, int n,
                                                int* __restrict__ bsum) {
    int i = blockIdx.x * 1024 + threadIdx.x;
    int v = (i < n) ? counts[i] : 0;
    #pragma unroll
    for (int d = 1; d < 64; d <<= 1) v += __shfl_xor(v, d);
    __shared__ int wsum[16];
    if ((threadIdx.x & 63) == 0) wsum[threadIdx.x >> 6] = v;
    __syncthreads();
    if (threadIdx.x < 16) {
        int s = wsum[threadIdx.x];
        #pragma unroll
        for (int d = 1; d < 16; d <<= 1) s += __shfl_xor(s, d, 16);
        if (threadIdx.x == 0) bsum[blockIdx.x] = s;
    }
}

// ---------- phase 2: exclusive scan of block sums (1 tiny block) ----------
__global__ __launch_bounds__(1024) void k_scan2(const int* __restrict__ bsum,
                                                int* __restrict__ bpre, int nb) {
    __shared__ int sh[1024];
    int t = threadIdx.x;
    int v = (t < nb) ? bsum[t] : 0;
    sh[t] = v;
    __syncthreads();
    for (int d = 1; d < 1024; d <<= 1) {
        int u = (t >= d) ? sh[t - d] : 0;
        __syncthreads();
        sh[t] += u;
        __syncthreads();
    }
    if (t < nb) bpre[t] = sh[t] - v;   // exclusive prefix
}

// ---------- phase 3: intra-block exclusive scan + write off/cursor/isd ----------
__global__ __launch_bounds__(1024) void k_scan3(const int* __restrict__ counts,
                                                const int* __restrict__ bpre,
                                                int* __restrict__ off,
                                                int* __restrict__ cursor,
                                                float* __restrict__ isd, int n) {
    __shared__ int woff[17];
    int i = blockIdx.x * 1024 + threadIdx.x;
    int lane = threadIdx.x & 63;
    int wv = threadIdx.x >> 6;
    int c = (i < n) ? counts[i] : 0;
    int v = c;
    #pragma unroll
    for (int d = 1; d < 64; d <<= 1) {      // intra-wave inclusive scan
        int u = __shfl_up(v, d);
        if (lane >= d) v += u;
    }
    if (lane == 63) woff[wv + 1] = v;        // wave totals
    if (threadIdx.x == 0) woff[0] = 0;
    __syncthreads();
    if (threadIdx.x == 0) {
        #pragma unroll
        for (int k = 1; k < 16; ++k) woff[k + 1] += woff[k];
    }
    __syncthreads();
    if (i < n) {
        int excl = v - c + woff[wv] + bpre[blockIdx.x];
        off[i] = excl;
        cursor[i] = excl;
        isd[i] = rsqrtf((float)(c > 1 ? c : 1));
        if (i == n - 1) off[n] = excl + c;
    }
}

// ---------- scatter edges into dst-sorted CSR (store src) ----------
__global__ void k_fill(const int* __restrict__ ei, int E,
                       int* __restrict__ cursor, int* __restrict__ csr) {
    int e = blockIdx.x * blockDim.x + threadIdx.x;
    if (e < E) {
        int dst = ei[E + e];
        int slot = atomicAdd(&cursor[dst], 1);
        csr[slot] = ei[e];
    }
}

// ---------- per-dst register aggregation of raw x (depth-2 pipelined) ----------
// wave = dst node, lane = x-feature. h[n, k*64+i] = (1/deg) * sum_e gw_k * x[src_e, i]
__global__ __launch_bounds__(256) void k_gather(const int* __restrict__ off,
                                                const int* __restrict__ csr,
                                                const float* __restrict__ isd,
                                                const float* __restrict__ x,
                                                const float* __restrict__ mu,
                                                const float* __restrict__ sigma,
                                                float* __restrict__ h, int n) {
    const int lane = threadIdx.x & 63;
    const int wid  = (blockIdx.x * blockDim.x + threadIdx.x) >> 6;
    const int nw   = (gridDim.x * blockDim.x) >> 6;
    float mu0[4], w0[4], mu1[4], w1[4];
    #pragma unroll
    for (int k = 0; k < 4; ++k) {
        mu0[k] = mu[2 * k];
        mu1[k] = mu[2 * k + 1];
        float s0 = sigma[2 * k], s1 = sigma[2 * k + 1];
        w0[k] = -0.5f / (EPS + s0 * s0);
        w1[k] = -0.5f / (EPS + s1 * s1);
    }
    for (int node = wid; node < n; node += nw) {
        const int base = off[node];
        const int len  = off[node + 1] - base;
        const float idd = isd[node];
        float e1[4];
        #pragma unroll
        for (int k = 0; k < 4; ++k) { float d = idd - mu1[k]; e1[k] = d * d * w1[k]; }
        float a0 = 0.f, a1 = 0.f, a2 = 0.f, a3 = 0.f;
        if (len > 0) {
            // software pipeline: index 2 ahead, data 1 ahead
            int   s_cur  = csr[base];
            float is_cur = isd[s_cur];
            float xv_cur = x[(size_t)s_cur * 64 + lane];
            int   s_nxt  = (len > 1) ? csr[base + 1] : s_cur;
            for (int j = 0; j < len; ++j) {
                int   s_n2  = (j + 2 < len) ? csr[base + j + 2] : s_nxt;
                float is_n  = isd[s_nxt];
                float xv_n  = x[(size_t)s_nxt * 64 + lane];
                float d0 = is_cur - mu0[0]; float g0 = __expf(d0 * d0 * w0[0] + e1[0]);
                float d1 = is_cur - mu0[1]; float g1 = __expf(d1 * d1 * w0[1] + e1[1]);
                float d2 = is_cur - mu0[2]; float g2 = __expf(d2 * d2 * w0[2] + e1[2]);
                float d3 = is_cur - mu0[3]; float g3 = __expf(d3 * d3 * w0[3] + e1[3]);
                a0 += g0 * xv_cur; a1 += g1 * xv_cur;
                a2 += g2 * xv_cur; a3 += g3 * xv_cur;
                is_cur = is_n; xv_cur = xv_n; s_nxt = s_n2;
            }
        }
        const float invd = 1.0f / (float)(len > 1 ? len : 1);
        size_t hb = (size_t)node * 256;
        h[hb + lane]        = a0 * invd;
        h[hb + 64 + lane]   = a1 * invd;
        h[hb + 128 + lane]  = a2 * invd;
        h[hb + 192 + lane]  = a3 * invd;
    }
}

// ---------- fused transform: out = x + relu(h@B + x@root + bias) ----------
// B[c][j] = g[c&63][(c>>6)*64 + j] staged in LDS (64 KB exactly).
// Wave tile = 16 rows; lane = output col j. dd loops unrolled x8 so 8
// independent ds_read_b32 are in flight before the 256 dependent VALU ops
// (latency-per-iteration fix; same fp order -> bit-identical).
__global__ __launch_bounds__(256, 2) void k_tx(const float* __restrict__ h,
                                               const float* __restrict__ x,
                                               const float* __restrict__ g,
                                               const float* __restrict__ root,
                                               const float* __restrict__ bias,
                                               float* __restrict__ out, int n) {
    __shared__ float Bs[256 * 64];
    for (int t = threadIdx.x; t < 4096; t += 256) {
        int idx = t * 4;
        int c = idx >> 6;
        int j = idx & 63;                  // multiple of 4
        int k = c >> 6, i = c & 63;
        *reinterpret_cast<float4*>(&Bs[idx]) =
            *reinterpret_cast<const float4*>(&g[i * 256 + k * 64 + j]);
    }
    __syncthreads();

    const int lane  = threadIdx.x & 63;
    const int w     = __builtin_amdgcn_readfirstlane(threadIdx.x >> 6);
    const int ntile = (n + 15) >> 4;
    const float bias_v = bias[lane];

    for (int tile = blockIdx.x * 4 + w; tile < ntile; tile += gridDim.x * 4) {
        const int r0 = tile * 16;
        float hvA[16], hvB[16], xv[16], acc[16];

        #pragma unroll
        for (int r = 0; r < 16; ++r) {
            int row = r0 + r; row = row < n ? row : n - 1;
            xv[r]  = x[(size_t)row * 64 + lane];
            hvA[r] = h[(size_t)row * 256 + lane];          // seg 0
            acc[r] = bias_v;
        }

        #pragma unroll
        for (int seg = 0; seg < 4; ++seg) {
            float (&cur)[16] = (seg & 1) ? hvB : hvA;
            float (&nxt)[16] = (seg & 1) ? hvA : hvB;
            if (seg < 3) {
                #pragma unroll
                for (int r = 0; r < 16; ++r) {
                    int row = r0 + r; row = row < n ? row : n - 1;
                    nxt[r] = h[(size_t)row * 256 + (seg + 1) * 64 + lane];
                }
            }
            const float* Brow = &Bs[seg * 64 * 64];
            #pragma unroll 8
            for (int dd = 0; dd < 64; ++dd) {
                float bB = Brow[dd * 64 + lane];           // stride-1 over lanes
                #pragma unroll
                for (int r = 0; r < 16; ++r)
                    acc[r] = fmaf(rl(cur[r], dd), bB, acc[r]);
            }
        }

        // x @ root part: root row dd is 256B, 16KB total -> L1-resident
        #pragma unroll 8
        for (int dd = 0; dd < 64; ++dd) {
            float rv = root[dd * 64 + lane];
            #pragma unroll
            for (int r = 0; r < 16; ++r)
                acc[r] = fmaf(rl(xv[r], dd), rv, acc[r]);
        }

        #pragma unroll
        for (int r = 0; r < 16; ++r) {
            int row = r0 + r;
            if (row < n) {
                float conv = acc[r];
                out[(size_t)row * 64 + lane] = xv[r] + (conv > 0.f ? conv : 0.f);
            }
        }
    }
}

extern "C" void kernel_launch(void* const* d_in, const int* in_sizes, int n_in,
                              void* d_out, int out_size, void* d_ws, size_t ws_size,
                              hipStream_t stream) {
    const float* x     = (const float*)d_in[0];
    const int*   ei    = (const int*)d_in[1];
    const float* g     = (const float*)d_in[2];
    const float* mu    = (const float*)d_in[3];
    const float* sigma = (const float*)d_in[4];
    const float* root  = (const float*)d_in[5];
    const float* bias  = (const float*)d_in[6];
    float* out = (float*)d_out;

    const int n = in_sizes[0] / 64;   // 100000
    const int E = in_sizes[1] / 2;    // 1600000
    const int nb = (n + 1023) / 1024; // scan blocks (98)

    // ws layout (4B units):
    //   counts[n] | off[n+4] | cursor[n] | isd[n] | bsum[128] | bpre[128] | csr[E] | h[n*256]
    // h offset = 4n+4+256+E floats -> 8,001,040 B (16B-aligned). Total ≈ 110.4 MB.
    int*   counts = (int*)d_ws;
    int*   off    = counts + n;
    int*   cursor = off + n + 4;
    float* isd    = (float*)(cursor + n);
    int*   bsum   = (int*)(isd + n);
    int*   bpre   = bsum + 128;
    int*   csr    = bpre + 128;
    float* h      = (float*)(csr + E);

    hipMemsetAsync(counts, 0, (size_t)n * sizeof(int), stream);

    k_hist<<<(E + 255) / 256, 256, 0, stream>>>(ei, E, counts);
    k_scan1<<<nb, 1024, 0, stream>>>(counts, n, bsum);
    k_scan2<<<1, 1024, 0, stream>>>(bsum, bpre, nb);
    k_scan3<<<nb, 1024, 0, stream>>>(counts, bpre, off, cursor, isd, n);
    k_fill<<<(E + 255) / 256, 256, 0, stream>>>(ei, E, cursor, csr);
    k_gather<<<2048, 256, 0, stream>>>(off, csr, isd, x, mu, sigma, h, n);
    k_tx<<<512, 256, 0, stream>>>(h, x, g, root, bias, out, n);
}

// Round 10
// 458.873 us; speedup vs baseline: 1.3025x; 1.3025x over previous
//
#include <hip/hip_runtime.h>

#define EPS 1e-15f

typedef __attribute__((ext_vector_type(8))) short short8;
typedef __attribute__((ext_vector_type(4))) float f32x4;

__device__ __forceinline__ unsigned short f2bf(float f) {       // RNE
    unsigned u = __float_as_uint(f);
    u = (u + 0x7FFF + ((u >> 16) & 1)) >> 16;
    return (unsigned short)u;
}
__device__ __forceinline__ float bf2f(unsigned short h) {
    return __uint_as_float(((unsigned)h) << 16);
}

// ---------- in-degree histogram (int counts) ----------
__global__ void k_hist(const int* __restrict__ ei, int E, int* __restrict__ counts) {
    int e = blockIdx.x * blockDim.x + threadIdx.x;
    if (e < E) atomicAdd(&counts[ei[E + e]], 1);
}

// ---------- parallel scan, phase 1: per-block sums (1024 elems/block) ----------
__global__ __launch_bounds__(1024) void k_scan1(const int* __restrict__ counts, int n,
                                                int* __restrict__ bsum) {
    int i = blockIdx.x * 1024 + threadIdx.x;
    int v = (i < n) ? counts[i] : 0;
    #pragma unroll
    for (int d = 1; d < 64; d <<= 1) v += __shfl_xor(v, d);
    __shared__ int wsum[16];
    if ((threadIdx.x & 63) == 0) wsum[threadIdx.x >> 6] = v;
    __syncthreads();
    if (threadIdx.x < 16) {
        int s = wsum[threadIdx.x];
        #pragma unroll
        for (int d = 1; d < 16; d <<= 1) s += __shfl_xor(s, d, 16);
        if (threadIdx.x == 0) bsum[blockIdx.x] = s;
    }
}

// ---------- phase 2: exclusive scan of block sums (1 tiny block) ----------
__global__ __launch_bounds__(1024) void k_scan2(const int* __restrict__ bsum,
                                                int* __restrict__ bpre, int nb) {
    __shared__ int sh[1024];
    int t = threadIdx.x;
    int v = (t < nb) ? bsum[t] : 0;
    sh[t] = v;
    __syncthreads();
    for (int d = 1; d < 1024; d <<= 1) {
        int u = (t >= d) ? sh[t - d] : 0;
        __syncthreads();
        sh[t] += u;
        __syncthreads();
    }
    if (t < nb) bpre[t] = sh[t] - v;   // exclusive prefix
}

// ---------- phase 3: intra-block exclusive scan + write off/cursor/isd ----------
__global__ __launch_bounds__(1024) void k_scan3(const int* __restrict__ counts,
                                                const int* __restrict__ bpre,
                                                int* __restrict__ off,
                                                int* __restrict__ cursor,
                                                float* __restrict__ isd, int n) {
    __shared__ int woff[17];
    int i = blockIdx.x * 1024 + threadIdx.x;
    int lane = threadIdx.x & 63;
    int wv = threadIdx.x >> 6;
    int c = (i < n) ? counts[i] : 0;
    int v = c;
    #pragma unroll
    for (int d = 1; d < 64; d <<= 1) {      // intra-wave inclusive scan
        int u = __shfl_up(v, d);
        if (lane >= d) v += u;
    }
    if (lane == 63) woff[wv + 1] = v;        // wave totals
    if (threadIdx.x == 0) woff[0] = 0;
    __syncthreads();
    if (threadIdx.x == 0) {
        #pragma unroll
        for (int k = 1; k < 16; ++k) woff[k + 1] += woff[k];
    }
    __syncthreads();
    if (i < n) {
        int excl = v - c + woff[wv] + bpre[blockIdx.x];
        off[i] = excl;
        cursor[i] = excl;
        isd[i] = rsqrtf((float)(c > 1 ? c : 1));
        if (i == n - 1) off[n] = excl + c;
    }
}

// ---------- scatter edges into dst-sorted CSR (store src) ----------
__global__ void k_fill(const int* __restrict__ ei, int E,
                       int* __restrict__ cursor, int* __restrict__ csr) {
    int e = blockIdx.x * blockDim.x + threadIdx.x;
    if (e < E) {
        int dst = ei[E + e];
        int slot = atomicAdd(&cursor[dst], 1);
        csr[slot] = ei[e];
    }
}

// ---------- per-dst register aggregation of raw x (depth-2 pipelined) ----------
__global__ __launch_bounds__(256) void k_gather(const int* __restrict__ off,
                                                const int* __restrict__ csr,
                                                const float* __restrict__ isd,
                                                const float* __restrict__ x,
                                                const float* __restrict__ mu,
                                                const float* __restrict__ sigma,
                                                float* __restrict__ h, int n) {
    const int lane = threadIdx.x & 63;
    const int wid  = (blockIdx.x * blockDim.x + threadIdx.x) >> 6;
    const int nw   = (gridDim.x * blockDim.x) >> 6;
    float mu0[4], w0[4], mu1[4], w1[4];
    #pragma unroll
    for (int k = 0; k < 4; ++k) {
        mu0[k] = mu[2 * k];
        mu1[k] = mu[2 * k + 1];
        float s0 = sigma[2 * k], s1 = sigma[2 * k + 1];
        w0[k] = -0.5f / (EPS + s0 * s0);
        w1[k] = -0.5f / (EPS + s1 * s1);
    }
    for (int node = wid; node < n; node += nw) {
        const int base = off[node];
        const int len  = off[node + 1] - base;
        const float idd = isd[node];
        float e1[4];
        #pragma unroll
        for (int k = 0; k < 4; ++k) { float d = idd - mu1[k]; e1[k] = d * d * w1[k]; }
        float a0 = 0.f, a1 = 0.f, a2 = 0.f, a3 = 0.f;
        if (len > 0) {
            int   s_cur  = csr[base];
            float is_cur = isd[s_cur];
            float xv_cur = x[(size_t)s_cur * 64 + lane];
            int   s_nxt  = (len > 1) ? csr[base + 1] : s_cur;
            for (int j = 0; j < len; ++j) {
                int   s_n2  = (j + 2 < len) ? csr[base + j + 2] : s_nxt;
                float is_n  = isd[s_nxt];
                float xv_n  = x[(size_t)s_nxt * 64 + lane];
                float d0 = is_cur - mu0[0]; float g0 = __expf(d0 * d0 * w0[0] + e1[0]);
                float d1 = is_cur - mu0[1]; float g1 = __expf(d1 * d1 * w0[1] + e1[1]);
                float d2 = is_cur - mu0[2]; float g2 = __expf(d2 * d2 * w0[2] + e1[2]);
                float d3 = is_cur - mu0[3]; float g3 = __expf(d3 * d3 * w0[3] + e1[3]);
                a0 += g0 * xv_cur; a1 += g1 * xv_cur;
                a2 += g2 * xv_cur; a3 += g3 * xv_cur;
                is_cur = is_n; xv_cur = xv_n; s_nxt = s_n2;
            }
        }
        const float invd = 1.0f / (float)(len > 1 ? len : 1);
        size_t hb = (size_t)node * 256;
        h[hb + lane]        = a0 * invd;
        h[hb + 64 + lane]   = a1 * invd;
        h[hb + 128 + lane]  = a2 * invd;
        h[hb + 192 + lane]  = a3 * invd;
    }
}

// ---------- pack combined B = [B_g ; root] (320x64) into MFMA fragment order ----------
// For chunk c (k-block of 32), col-tile t, lane l, elem i:
//   kk = c*32 + (l>>4)*8 + i, j = t*16 + (l&15)
//   Bc[kk][j] = (kk<256) ? g[kk&63][(kk>>6)*64 + j] : root[(kk-256)*64 + j]
// stored at Bpk[(((c*4+t)*64)+l)*8 + i] as bf16 hi and lo halves.
__global__ void k_packB(const float* __restrict__ g, const float* __restrict__ root,
                        unsigned short* __restrict__ Bhi, unsigned short* __restrict__ Blo) {
    int idx = blockIdx.x * 256 + threadIdx.x;      // 0..20479
    if (idx >= 20480) return;
    int i  = idx & 7;
    int l  = (idx >> 3) & 63;
    int ct = idx >> 9;                              // c*4 + t
    int c = ct >> 2, t = ct & 3;
    int kk = c * 32 + ((l >> 4) & 3) * 8 + i;
    int j  = t * 16 + (l & 15);
    float v = (kk < 256) ? g[(kk & 63) * 256 + (kk >> 6) * 64 + j]
                         : root[(kk - 256) * 64 + j];
    unsigned short hi = f2bf(v);
    unsigned short lo = f2bf(v - bf2f(hi));
    Bhi[idx] = hi;
    Blo[idx] = lo;
}

// ---------- MFMA transform: out = x + relu([h|x] @ Bc + bias) ----------
// One wave per 16-row strip; split-bf16 (hi/lo) 3-pass for fp32-grade accuracy.
// No LDS. A frags loaded per-lane from h/x; B frags from packed L2-resident arrays.
__global__ __launch_bounds__(256) void k_tx_mfma(const float* __restrict__ h,
                                                 const float* __restrict__ x,
                                                 const unsigned short* __restrict__ Bhi,
                                                 const unsigned short* __restrict__ Blo,
                                                 const float* __restrict__ bias,
                                                 float* __restrict__ out, int n) {
    const int lane  = threadIdx.x & 63;
    const int strip = blockIdx.x * 4 + (threadIdx.x >> 6);
    const int nstrip = (n + 15) >> 4;
    if (strip >= nstrip) return;
    const int r0 = strip * 16;
    const int arow = r0 + (lane & 15);             // A-fragment row
    const int kgrp = (lane >> 4) * 8;              // k offset within chunk

    f32x4 acc[4];
    #pragma unroll
    for (int t = 0; t < 4; ++t) acc[t] = (f32x4){0.f, 0.f, 0.f, 0.f};

    const int arowc = arow < n ? arow : n - 1;     // clamp (tail-safe loads)

    #pragma unroll
    for (int c = 0; c < 10; ++c) {
        const float* ap = (c < 8)
            ? (h + (size_t)arowc * 256 + c * 32 + kgrp)
            : (x + (size_t)arowc * 64 + (c - 8) * 32 + kgrp);
        float4 p0 = *reinterpret_cast<const float4*>(ap);
        float4 p1 = *reinterpret_cast<const float4*>(ap + 4);
        float av[8] = {p0.x, p0.y, p0.z, p0.w, p1.x, p1.y, p1.z, p1.w};
        short8 ahi, alo;
        #pragma unroll
        for (int i = 0; i < 8; ++i) {
            unsigned short hi = f2bf(av[i]);
            ahi[i] = (short)hi;
            alo[i] = (short)f2bf(av[i] - bf2f(hi));
        }
        #pragma unroll
        for (int t = 0; t < 4; ++t) {
            const int boff = ((c * 4 + t) * 64 + lane) * 8;
            short8 bhi = *reinterpret_cast<const short8*>(Bhi + boff);
            short8 blo = *reinterpret_cast<const short8*>(Blo + boff);
            acc[t] = __builtin_amdgcn_mfma_f32_16x16x32_bf16(ahi, bhi, acc[t], 0, 0, 0);
            acc[t] = __builtin_amdgcn_mfma_f32_16x16x32_bf16(alo, bhi, acc[t], 0, 0, 0);
            acc[t] = __builtin_amdgcn_mfma_f32_16x16x32_bf16(ahi, blo, acc[t], 0, 0, 0);
        }
    }

    // epilogue: D row = (lane>>4)*4 + q, col = t*16 + (lane&15)
    const int lq = (lane >> 4) * 4;
    const int lc = lane & 15;
    #pragma unroll
    for (int t = 0; t < 4; ++t) {
        const int col = t * 16 + lc;
        const float bv = bias[col];
        #pragma unroll
        for (int q = 0; q < 4; ++q) {
            const int row = r0 + lq + q;
            if (row < n) {
                const size_t o = (size_t)row * 64 + col;
                float xres = x[o];
                float conv = acc[t][q] + bv;
                out[o] = xres + (conv > 0.f ? conv : 0.f);
            }
        }
    }
}

extern "C" void kernel_launch(void* const* d_in, const int* in_sizes, int n_in,
                              void* d_out, int out_size, void* d_ws, size_t ws_size,
                              hipStream_t stream) {
    const float* x     = (const float*)d_in[0];
    const int*   ei    = (const int*)d_in[1];
    const float* g     = (const float*)d_in[2];
    const float* mu    = (const float*)d_in[3];
    const float* sigma = (const float*)d_in[4];
    const float* root  = (const float*)d_in[5];
    const float* bias  = (const float*)d_in[6];
    float* out = (float*)d_out;

    const int n = in_sizes[0] / 64;   // 100000
    const int E = in_sizes[1] / 2;    // 1600000
    const int nb = (n + 1023) / 1024; // scan blocks (98)

    // ws layout (4B units):
    //   counts[n] | off[n+4] | cursor[n] | isd[n] | bsum[128] | bpre[128]
    //   | Bhi[5120] | Blo[5120] | csr[E] | h[n*256]
    // h byte offset = (4n+4+256+10240+E)*4 = 8,042,000 B (16B-aligned).
    int*   counts = (int*)d_ws;
    int*   off    = counts + n;
    int*   cursor = off + n + 4;
    float* isd    = (float*)(cursor + n);
    int*   bsum   = (int*)(isd + n);
    int*   bpre   = bsum + 128;
    unsigned short* Bhi = (unsigned short*)(bpre + 128);   // 20480 ushort
    unsigned short* Blo = Bhi + 20480;
    int*   csr    = (int*)(Blo + 20480);
    float* h      = (float*)(csr + E);

    hipMemsetAsync(counts, 0, (size_t)n * sizeof(int), stream);

    k_hist<<<(E + 255) / 256, 256, 0, stream>>>(ei, E, counts);
    k_scan1<<<nb, 1024, 0, stream>>>(counts, n, bsum);
    k_scan2<<<1, 1024, 0, stream>>>(bsum, bpre, nb);
    k_scan3<<<nb, 1024, 0, stream>>>(counts, bpre, off, cursor, isd, n);
    k_fill<<<(E + 255) / 256, 256, 0, stream>>>(ei, E, cursor, csr);
    k_packB<<<80, 256, 0, stream>>>(g, root, Bhi, Blo);
    k_gather<<<2048, 256, 0, stream>>>(off, csr, isd, x, mu, sigma, h, n);
    const int nstrip = (n + 15) / 16;
    k_tx_mfma<<<(nstrip + 3) / 4, 256, 0, stream>>>(h, x, Bhi, Blo, bias, out, n);
}

// Round 13
// 446.638 us; speedup vs baseline: 1.3382x; 1.0274x over previous
//
#include <hip/hip_runtime.h>

#define EPS 1e-15f

typedef __attribute__((ext_vector_type(8))) short short8;
typedef __attribute__((ext_vector_type(4))) float f32x4;

__device__ __forceinline__ unsigned short f2bf(float f) {       // RNE
    unsigned u = __float_as_uint(f);
    u = (u + 0x7FFF + ((u >> 16) & 1)) >> 16;
    return (unsigned short)u;
}
__device__ __forceinline__ float bf2f(unsigned short h) {
    return __uint_as_float(((unsigned)h) << 16);
}

// ---------- in-degree histogram (int counts) ----------
__global__ void k_hist(const int* __restrict__ ei, int E, int* __restrict__ counts) {
    int e = blockIdx.x * blockDim.x + threadIdx.x;
    if (e < E) atomicAdd(&counts[ei[E + e]], 1);
}

// ---------- parallel scan, phase 1: per-block sums ----------
__global__ __launch_bounds__(1024) void k_scan1(const int* __restrict__ counts, int n,
                                                int* __restrict__ bsum) {
    int i = blockIdx.x * 1024 + threadIdx.x;
    int v = (i < n) ? counts[i] : 0;
    #pragma unroll
    for (int d = 1; d < 64; d <<= 1) v += __shfl_xor(v, d);
    __shared__ int wsum[16];
    if ((threadIdx.x & 63) == 0) wsum[threadIdx.x >> 6] = v;
    __syncthreads();
    if (threadIdx.x < 16) {
        int s = wsum[threadIdx.x];
        #pragma unroll
        for (int d = 1; d < 16; d <<= 1) s += __shfl_xor(s, d, 16);
        if (threadIdx.x == 0) bsum[blockIdx.x] = s;
    }
}

// ---------- phase 2: exclusive scan of block sums ----------
__global__ __launch_bounds__(1024) void k_scan2(const int* __restrict__ bsum,
                                                int* __restrict__ bpre, int nb) {
    __shared__ int sh[1024];
    int t = threadIdx.x;
    int v = (t < nb) ? bsum[t] : 0;
    sh[t] = v;
    __syncthreads();
    for (int d = 1; d < 1024; d <<= 1) {
        int u = (t >= d) ? sh[t - d] : 0;
        __syncthreads();
        sh[t] += u;
        __syncthreads();
    }
    if (t < nb) bpre[t] = sh[t] - v;
}

// ---------- phase 3: intra-block scan + write off/cursor/isd ----------
__global__ __launch_bounds__(1024) void k_scan3(const int* __restrict__ counts,
                                                const int* __restrict__ bpre,
                                                int* __restrict__ off,
                                                int* __restrict__ cursor,
                                                float* __restrict__ isd, int n) {
    __shared__ int woff[17];
    int i = blockIdx.x * 1024 + threadIdx.x;
    int lane = threadIdx.x & 63;
    int wv = threadIdx.x >> 6;
    int c = (i < n) ? counts[i] : 0;
    int v = c;
    #pragma unroll
    for (int d = 1; d < 64; d <<= 1) {
        int u = __shfl_up(v, d);
        if (lane >= d) v += u;
    }
    if (lane == 63) woff[wv + 1] = v;
    if (threadIdx.x == 0) woff[0] = 0;
    __syncthreads();
    if (threadIdx.x == 0) {
        #pragma unroll
        for (int k = 1; k < 16; ++k) woff[k + 1] += woff[k];
    }
    __syncthreads();
    if (i < n) {
        int excl = v - c + woff[wv] + bpre[blockIdx.x];
        off[i] = excl;
        cursor[i] = excl;
        isd[i] = rsqrtf((float)(c > 1 ? c : 1));
        if (i == n - 1) off[n] = excl + c;
    }
}

// ---------- per-node separable Gaussian factors ----------
// A_k[i] = exp(w0_k*(isd_i-mu0_k)^2), B_k[i] = exp(w1_k*(isd_i-mu1_k)^2)
__global__ void k_AB(const float* __restrict__ isd, const float* __restrict__ mu,
                     const float* __restrict__ sigma,
                     float4* __restrict__ A4, float4* __restrict__ B4, int n) {
    int i = blockIdx.x * 256 + threadIdx.x;
    if (i >= n) return;
    float v = isd[i];
    float a[4], b[4];
    #pragma unroll
    for (int k = 0; k < 4; ++k) {
        float s0 = sigma[2 * k], s1 = sigma[2 * k + 1];
        float w0 = -0.5f / (EPS + s0 * s0);
        float w1 = -0.5f / (EPS + s1 * s1);
        float d0 = v - mu[2 * k];
        float d1 = v - mu[2 * k + 1];
        a[k] = __expf(d0 * d0 * w0);
        b[k] = __expf(d1 * d1 * w1);
    }
    A4[i] = (float4){a[0], a[1], a[2], a[3]};
    B4[i] = (float4){b[0], b[1], b[2], b[3]};
}

// ---------- scatter edges into dst-sorted CSR (store src) ----------
__global__ void k_fill(const int* __restrict__ ei, int E,
                       int* __restrict__ cursor, int* __restrict__ csr) {
    int e = blockIdx.x * blockDim.x + threadIdx.x;
    if (e < E) {
        int dst = ei[E + e];
        int slot = atomicAdd(&cursor[dst], 1);
        csr[slot] = ei[e];
    }
}

// ---------- per-dst aggregation: h[dst,k*64+i] = B_k*invd * sum_j A_k[src]*x[src,i] ----------
__global__ __launch_bounds__(256) void k_gather(const int* __restrict__ off,
                                                const int* __restrict__ csr,
                                                const float4* __restrict__ A4,
                                                const float4* __restrict__ B4,
                                                const float* __restrict__ x,
                                                float* __restrict__ h, int n) {
    const int lane = threadIdx.x & 63;
    const int wid  = (blockIdx.x * blockDim.x + threadIdx.x) >> 6;
    const int nw   = (gridDim.x * blockDim.x) >> 6;
    for (int node = wid; node < n; node += nw) {
        const int base = off[node];
        const int len  = off[node + 1] - base;
        float a0 = 0.f, a1 = 0.f, a2 = 0.f, a3 = 0.f;
        if (len > 0) {
            int    s_cur  = csr[base];
            float4 A_cur  = A4[s_cur];
            float  xv_cur = x[(size_t)s_cur * 64 + lane];
            int    s_nxt  = (len > 1) ? csr[base + 1] : s_cur;
            for (int j = 0; j < len; ++j) {
                int    s_n2 = (j + 2 < len) ? csr[base + j + 2] : s_nxt;
                float4 A_n  = A4[s_nxt];
                float  xv_n = x[(size_t)s_nxt * 64 + lane];
                a0 = fmaf(A_cur.x, xv_cur, a0);
                a1 = fmaf(A_cur.y, xv_cur, a1);
                a2 = fmaf(A_cur.z, xv_cur, a2);
                a3 = fmaf(A_cur.w, xv_cur, a3);
                A_cur = A_n; xv_cur = xv_n; s_nxt = s_n2;
            }
        }
        const float invd = 1.0f / (float)(len > 1 ? len : 1);
        float4 Bv = B4[node];
        float s0 = Bv.x * invd, s1 = Bv.y * invd, s2 = Bv.z * invd, s3 = Bv.w * invd;
        size_t hb = (size_t)node * 256;
        h[hb + lane]       = a0 * s0;
        h[hb + 64 + lane]  = a1 * s1;
        h[hb + 128 + lane] = a2 * s2;
        h[hb + 192 + lane] = a3 * s3;
    }
}

// ---------- pack combined B = [B_g ; root] (320x64) into MFMA fragment order ----------
__global__ void k_packB(const float* __restrict__ g, const float* __restrict__ root,
                        unsigned short* __restrict__ Bhi, unsigned short* __restrict__ Blo) {
    int idx = blockIdx.x * 256 + threadIdx.x;      // 0..20479
    if (idx >= 20480) return;
    int i  = idx & 7;
    int l  = (idx >> 3) & 63;
    int ct = idx >> 9;                              // c*4 + t
    int c = ct >> 2, t = ct & 3;
    int kk = c * 32 + ((l >> 4) & 3) * 8 + i;
    int j  = t * 16 + (l & 15);
    float v = (kk < 256) ? g[(kk & 63) * 256 + (kk >> 6) * 64 + j]
                         : root[(kk - 256) * 64 + j];
    unsigned short hi = f2bf(v);
    unsigned short lo = f2bf(v - bf2f(hi));
    Bhi[idx] = hi;
    Blo[idx] = lo;
}

// ---------- MFMA transform: out = x + relu([h|x] @ Bc + bias) ----------
__global__ __launch_bounds__(256) void k_tx_mfma(const float* __restrict__ h,
                                                 const float* __restrict__ x,
                                                 const unsigned short* __restrict__ Bhi,
                                                 const unsigned short* __restrict__ Blo,
                                                 const float* __restrict__ bias,
                                                 float* __restrict__ out, int n) {
    const int lane  = threadIdx.x & 63;
    const int strip = blockIdx.x * 4 + (threadIdx.x >> 6);
    const int nstrip = (n + 15) >> 4;
    if (strip >= nstrip) return;
    const int r0 = strip * 16;
    const int arow = r0 + (lane & 15);
    const int kgrp = (lane >> 4) * 8;

    f32x4 acc[4];
    #pragma unroll
    for (int t = 0; t < 4; ++t) acc[t] = (f32x4){0.f, 0.f, 0.f, 0.f};

    const int arowc = arow < n ? arow : n - 1;

    #pragma unroll
    for (int c = 0; c < 10; ++c) {
        const float* ap = (c < 8)
            ? (h + (size_t)arowc * 256 + c * 32 + kgrp)
            : (x + (size_t)arowc * 64 + (c - 8) * 32 + kgrp);
        float4 p0 = *reinterpret_cast<const float4*>(ap);
        float4 p1 = *reinterpret_cast<const float4*>(ap + 4);
        float av[8] = {p0.x, p0.y, p0.z, p0.w, p1.x, p1.y, p1.z, p1.w};
        short8 ahi, alo;
        #pragma unroll
        for (int i = 0; i < 8; ++i) {
            unsigned short hi = f2bf(av[i]);
            ahi[i] = (short)hi;
            alo[i] = (short)f2bf(av[i] - bf2f(hi));
        }
        #pragma unroll
        for (int t = 0; t < 4; ++t) {
            const int boff = ((c * 4 + t) * 64 + lane) * 8;
            short8 bhi = *reinterpret_cast<const short8*>(Bhi + boff);
            short8 blo = *reinterpret_cast<const short8*>(Blo + boff);
            acc[t] = __builtin_amdgcn_mfma_f32_16x16x32_bf16(ahi, bhi, acc[t], 0, 0, 0);
            acc[t] = __builtin_amdgcn_mfma_f32_16x16x32_bf16(alo, bhi, acc[t], 0, 0, 0);
            acc[t] = __builtin_amdgcn_mfma_f32_16x16x32_bf16(ahi, blo, acc[t], 0, 0, 0);
        }
    }

    const int lq = (lane >> 4) * 4;
    const int lc = lane & 15;
    #pragma unroll
    for (int t = 0; t < 4; ++t) {
        const int col = t * 16 + lc;
        const float bv = bias[col];
        #pragma unroll
        for (int q = 0; q < 4; ++q) {
            const int row = r0 + lq + q;
            if (row < n) {
                const size_t o = (size_t)row * 64 + col;
                float xres = x[o];
                float conv = acc[t][q] + bv;
                out[o] = xres + (conv > 0.f ? conv : 0.f);
            }
        }
    }
}

extern "C" void kernel_launch(void* const* d_in, const int* in_sizes, int n_in,
                              void* d_out, int out_size, void* d_ws, size_t ws_size,
                              hipStream_t stream) {
    const float* x     = (const float*)d_in[0];
    const int*   ei    = (const int*)d_in[1];
    const float* g     = (const float*)d_in[2];
    const float* mu    = (const float*)d_in[3];
    const float* sigma = (const float*)d_in[4];
    const float* root  = (const float*)d_in[5];
    const float* bias  = (const float*)d_in[6];
    float* out = (float*)d_out;

    const int n = in_sizes[0] / 64;   // 100000
    const int E = in_sizes[1] / 2;    // 1600000
    const int nb = (n + 1023) / 1024; // scan blocks (98)

    // ws layout (bytes): counts 4n | off 4n+16 | cursor 4n | isd 4n | bsum 512 |
    //   bpre 512 | Bhi 40960 | Blo 40960 | A4 16n | B4 16n | csr 4E | h 1024n
    // A4 offset = 1,682,960 B (16-aligned); h offset = 11,282,960 B (16-aligned).
    int*   counts = (int*)d_ws;
    int*   off    = counts + n;
    int*   cursor = off + n + 4;
    float* isd    = (float*)(cursor + n);
    int*   bsum   = (int*)(isd + n);
    int*   bpre   = bsum + 128;
    unsigned short* Bhi = (unsigned short*)(bpre + 128);   // 20480 ushort
    unsigned short* Blo = Bhi + 20480;
    float4* A4    = (float4*)(Blo + 20480);
    float4* B4    = A4 + n;
    int*   csr    = (int*)(B4 + n);
    float* h      = (float*)(csr + E);

    hipMemsetAsync(counts, 0, (size_t)n * sizeof(int), stream);

    k_hist<<<(E + 255) / 256, 256, 0, stream>>>(ei, E, counts);
    k_scan1<<<nb, 1024, 0, stream>>>(counts, n, bsum);
    k_scan2<<<1, 1024, 0, stream>>>(bsum, bpre, nb);
    k_scan3<<<nb, 1024, 0, stream>>>(counts, bpre, off, cursor, isd, n);
    k_AB<<<(n + 255) / 256, 256, 0, stream>>>(isd, mu, sigma, A4, B4, n);
    k_fill<<<(E + 255) / 256, 256, 0, stream>>>(ei, E, cursor, csr);
    k_packB<<<80, 256, 0, stream>>>(g, root, Bhi, Blo);
    k_gather<<<2048, 256, 0, stream>>>(off, csr, A4, B4, x, h, n);
    const int nstrip = (n + 15) / 16;
    k_tx_mfma<<<(nstrip + 3) / 4, 256, 0, stream>>>(h, x, Bhi, Blo, bias, out, n);
}

// Round 14
// 380.163 us; speedup vs baseline: 1.5721x; 1.1749x over previous
//
#include <hip/hip_runtime.h>

#define EPS 1e-15f
#define CAP 32
#define HSTR 272   // LDS row stride (floats): 16B-aligned, 2-way-bank-free for MFMA reads

typedef __attribute__((ext_vector_type(8))) short short8;
typedef __attribute__((ext_vector_type(4))) float f32x4;

__device__ __forceinline__ unsigned short f2bf(float f) {       // RNE
    unsigned u = __float_as_uint(f);
    u = (u + 0x7FFF + ((u >> 16) & 1)) >> 16;
    return (unsigned short)u;
}
__device__ __forceinline__ float bf2f(unsigned short h) {
    return __uint_as_float(((unsigned)h) << 16);
}

// ---------- single-pass padded-CSR fill (replaces hist+scan+fill) ----------
__global__ void k_fill2(const int* __restrict__ ei, int E, int* __restrict__ cnt,
                        int* __restrict__ csrp, int* __restrict__ ovf,
                        int* __restrict__ ovfcnt) {
    int e = blockIdx.x * blockDim.x + threadIdx.x;
    if (e < E) {
        int src = ei[e];
        int dst = ei[E + e];
        int slot = atomicAdd(&cnt[dst], 1);
        if (slot < CAP) {
            csrp[dst * CAP + slot] = src;
        } else {                                  // rare (P(deg>32) ~ 1e-4)
            int o = atomicAdd(ovfcnt, 1);
            ovf[2 * o] = src;
            ovf[2 * o + 1] = dst;
        }
    }
}

// ---------- per-node separable Gaussian factors (isd from cnt) ----------
__global__ void k_AB(const int* __restrict__ cnt, const float* __restrict__ mu,
                     const float* __restrict__ sigma,
                     float4* __restrict__ A4, float4* __restrict__ B4, int n) {
    int i = blockIdx.x * 256 + threadIdx.x;
    if (i >= n) return;
    int c = cnt[i];
    float v = rsqrtf((float)(c > 1 ? c : 1));
    float a[4], b[4];
    #pragma unroll
    for (int k = 0; k < 4; ++k) {
        float s0 = sigma[2 * k], s1 = sigma[2 * k + 1];
        float w0 = -0.5f / (EPS + s0 * s0);
        float w1 = -0.5f / (EPS + s1 * s1);
        float d0 = v - mu[2 * k];
        float d1 = v - mu[2 * k + 1];
        a[k] = __expf(d0 * d0 * w0);
        b[k] = __expf(d1 * d1 * w1);
    }
    A4[i] = (float4){a[0], a[1], a[2], a[3]};
    B4[i] = (float4){b[0], b[1], b[2], b[3]};
}

// ---------- pack combined B = [B_g ; root] (320x64) into MFMA fragment order ----------
__global__ void k_packB(const float* __restrict__ g, const float* __restrict__ root,
                        unsigned short* __restrict__ Bhi, unsigned short* __restrict__ Blo) {
    int idx = blockIdx.x * 256 + threadIdx.x;      // 0..20479
    if (idx >= 20480) return;
    int i  = idx & 7;
    int l  = (idx >> 3) & 63;
    int ct = idx >> 9;                              // c*4 + t
    int c = ct >> 2, t = ct & 3;
    int kk = c * 32 + ((l >> 4) & 3) * 8 + i;
    int j  = t * 16 + (l & 15);
    float v = (kk < 256) ? g[(kk & 63) * 256 + (kk >> 6) * 64 + j]
                         : root[(kk - 256) * 64 + j];
    unsigned short hi = f2bf(v);
    unsigned short lo = f2bf(v - bf2f(hi));
    Bhi[idx] = hi;
    Blo[idx] = lo;
}

// ---------- fused gather + MFMA transform ----------
// Block = 256 (4 waves) owns a 16-row strip. Phase 1: each wave gathers 4 nodes
// (per-dst weighted sums of x) into LDS h-strip. Phase 2: wave t computes output
// col-tile t via split-bf16 MFMA over [h|x] @ [Bg;root], fused bias/relu/residual.
// h never touches HBM (saves ~200 MB traffic vs separate kernels).
__global__ __launch_bounds__(256, 8) void k_fused(
    const int* __restrict__ cnt, const int* __restrict__ csrp,
    const int* __restrict__ ovf, const int* __restrict__ ovfcnt,
    const float4* __restrict__ A4, const float4* __restrict__ B4,
    const float* __restrict__ x,
    const unsigned short* __restrict__ Bhi, const unsigned short* __restrict__ Blo,
    const float* __restrict__ bias, float* __restrict__ out, int n) {
    __shared__ float hs[16 * HSTR];
    const int lane = threadIdx.x & 63;
    const int w    = threadIdx.x >> 6;             // 0..3
    const int r0   = blockIdx.x * 16;

    // ---- phase 1: gather 4 nodes per wave ----
    for (int q = 0; q < 4; ++q) {
        const int nd   = w * 4 + q;
        const int node = r0 + nd;
        float a0 = 0.f, a1 = 0.f, a2 = 0.f, a3 = 0.f;
        if (node < n) {
            const int len = cnt[node];
            const int m   = len < CAP ? len : CAP;
            const int* cp = csrp + (size_t)node * CAP;
            if (m > 0) {                            // depth-2 pipelined edge loop
                int    s_cur  = cp[0];
                float4 A_cur  = A4[s_cur];
                float  xv_cur = x[(size_t)s_cur * 64 + lane];
                int    s_nxt  = (m > 1) ? cp[1] : s_cur;
                for (int j = 0; j < m; ++j) {
                    int    s_n2 = (j + 2 < m) ? cp[j + 2] : s_nxt;
                    float4 A_n  = A4[s_nxt];
                    float  xv_n = x[(size_t)s_nxt * 64 + lane];
                    a0 = fmaf(A_cur.x, xv_cur, a0);
                    a1 = fmaf(A_cur.y, xv_cur, a1);
                    a2 = fmaf(A_cur.z, xv_cur, a2);
                    a3 = fmaf(A_cur.w, xv_cur, a3);
                    A_cur = A_n; xv_cur = xv_n; s_nxt = s_n2;
                }
            }
            if (len > CAP) {                        // rare overflow path
                const int no = *ovfcnt;
                for (int j = 0; j < no; ++j) {
                    int od = ovf[2 * j + 1];
                    if (od == node) {
                        int os = ovf[2 * j];
                        float4 Av = A4[os];
                        float  xv = x[(size_t)os * 64 + lane];
                        a0 = fmaf(Av.x, xv, a0);
                        a1 = fmaf(Av.y, xv, a1);
                        a2 = fmaf(Av.z, xv, a2);
                        a3 = fmaf(Av.w, xv, a3);
                    }
                }
            }
            const float invd = 1.0f / (float)(len > 1 ? len : 1);
            float4 Bv = B4[node];
            hs[nd * HSTR + lane]       = a0 * (Bv.x * invd);
            hs[nd * HSTR + 64 + lane]  = a1 * (Bv.y * invd);
            hs[nd * HSTR + 128 + lane] = a2 * (Bv.z * invd);
            hs[nd * HSTR + 192 + lane] = a3 * (Bv.w * invd);
        } else {
            hs[nd * HSTR + lane]       = 0.f;
            hs[nd * HSTR + 64 + lane]  = 0.f;
            hs[nd * HSTR + 128 + lane] = 0.f;
            hs[nd * HSTR + 192 + lane] = 0.f;
        }
    }
    __syncthreads();

    // ---- phase 2: wave w computes col-tile t = w ----
    const int t     = w;
    const int arow  = r0 + (lane & 15);
    const int arowc = arow < n ? arow : n - 1;
    const int kgrp  = (lane >> 4) * 8;
    f32x4 acc = (f32x4){0.f, 0.f, 0.f, 0.f};

    #pragma unroll
    for (int c = 0; c < 10; ++c) {
        float av[8];
        if (c < 8) {
            const float* ap = &hs[(lane & 15) * HSTR + c * 32 + kgrp];
            float4 p0 = *reinterpret_cast<const float4*>(ap);
            float4 p1 = *reinterpret_cast<const float4*>(ap + 4);
            av[0]=p0.x; av[1]=p0.y; av[2]=p0.z; av[3]=p0.w;
            av[4]=p1.x; av[5]=p1.y; av[6]=p1.z; av[7]=p1.w;
        } else {
            const float* ap = x + (size_t)arowc * 64 + (c - 8) * 32 + kgrp;
            float4 p0 = *reinterpret_cast<const float4*>(ap);
            float4 p1 = *reinterpret_cast<const float4*>(ap + 4);
            av[0]=p0.x; av[1]=p0.y; av[2]=p0.z; av[3]=p0.w;
            av[4]=p1.x; av[5]=p1.y; av[6]=p1.z; av[7]=p1.w;
        }
        short8 ahi, alo;
        #pragma unroll
        for (int i = 0; i < 8; ++i) {
            unsigned short hi = f2bf(av[i]);
            ahi[i] = (short)hi;
            alo[i] = (short)f2bf(av[i] - bf2f(hi));
        }
        const int boff = ((c * 4 + t) * 64 + lane) * 8;
        short8 bhi = *reinterpret_cast<const short8*>(Bhi + boff);
        short8 blo = *reinterpret_cast<const short8*>(Blo + boff);
        acc = __builtin_amdgcn_mfma_f32_16x16x32_bf16(ahi, bhi, acc, 0, 0, 0);
        acc = __builtin_amdgcn_mfma_f32_16x16x32_bf16(alo, bhi, acc, 0, 0, 0);
        acc = __builtin_amdgcn_mfma_f32_16x16x32_bf16(ahi, blo, acc, 0, 0, 0);
    }

    const int lq  = (lane >> 4) * 4;
    const int col = t * 16 + (lane & 15);
    const float bv = bias[col];
    #pragma unroll
    for (int q = 0; q < 4; ++q) {
        const int row = r0 + lq + q;
        if (row < n) {
            const size_t o = (size_t)row * 64 + col;
            float xres = x[o];
            float conv = acc[q] + bv;
            out[o] = xres + (conv > 0.f ? conv : 0.f);
        }
    }
}

extern "C" void kernel_launch(void* const* d_in, const int* in_sizes, int n_in,
                              void* d_out, int out_size, void* d_ws, size_t ws_size,
                              hipStream_t stream) {
    const float* x     = (const float*)d_in[0];
    const int*   ei    = (const int*)d_in[1];
    const float* g     = (const float*)d_in[2];
    const float* mu    = (const float*)d_in[3];
    const float* sigma = (const float*)d_in[4];
    const float* root  = (const float*)d_in[5];
    const float* bias  = (const float*)d_in[6];
    float* out = (float*)d_out;

    const int n = in_sizes[0] / 64;   // 100000
    const int E = in_sizes[1] / 2;    // 1600000

    // ws layout (ints/floats, 4B units):
    //   cnt[n] | ovfcnt[4] | Bhi 10240 | Blo 10240 | A4 4n | B4 4n | csrp 32n | ovf 2E
    // A4 byte offset = 400016+81920 = 481,936 (16B-aligned). Total ≈ 29.3 MB.
    int* cnt    = (int*)d_ws;
    int* ovfcnt = cnt + n;
    unsigned short* Bhi = (unsigned short*)(ovfcnt + 4);    // 20480 ushort
    unsigned short* Blo = Bhi + 20480;
    float4* A4  = (float4*)(Blo + 20480);
    float4* B4  = A4 + n;
    int* csrp   = (int*)(B4 + n);
    int* ovf    = csrp + (size_t)n * CAP;

    hipMemsetAsync(cnt, 0, (size_t)n * sizeof(int), stream);
    hipMemsetAsync(ovfcnt, 0, 4 * sizeof(int), stream);

    k_fill2<<<(E + 255) / 256, 256, 0, stream>>>(ei, E, cnt, csrp, ovf, ovfcnt);
    k_AB<<<(n + 255) / 256, 256, 0, stream>>>(cnt, mu, sigma, A4, B4, n);
    k_packB<<<80, 256, 0, stream>>>(g, root, Bhi, Blo);
    const int nstrip = (n + 15) / 16;
    k_fused<<<nstrip, 256, 0, stream>>>(cnt, csrp, ovf, ovfcnt, A4, B4, x,
                                        Bhi, Blo, bias, out, n);
}

// Round 16
// 357.174 us; speedup vs baseline: 1.6733x; 1.0644x over previous
//
#include <hip/hip_runtime.h>

#define EPS 1e-15f
#define CAP 32
#define NP 4          // dst-range passes for the CSR fill
#define HS2 264       // LDS row stride in shorts: 528B -> 4-bank row skew, conflict-free

typedef __attribute__((ext_vector_type(8))) short short8;
typedef __attribute__((ext_vector_type(4))) float f32x4;

__device__ __forceinline__ unsigned short f2bf(float f) {       // RNE
    unsigned u = __float_as_uint(f);
    u = (u + 0x7FFF + ((u >> 16) & 1)) >> 16;
    return (unsigned short)u;
}
__device__ __forceinline__ float bf2f(unsigned short h) {
    return __uint_as_float(((unsigned)h) << 16);
}

// ---------- padded-CSR fill, one dst-range per pass (write-locality fix) ----------
__global__ void k_fill2(const int* __restrict__ ei, int E, int dlo, int dhi,
                        int* __restrict__ cnt, int* __restrict__ csrp,
                        int* __restrict__ ovf, int* __restrict__ ovfcnt) {
    int e = blockIdx.x * blockDim.x + threadIdx.x;
    if (e < E) {
        int dst = ei[E + e];
        if (dst >= dlo && dst < dhi) {
            int src = ei[e];
            int slot = atomicAdd(&cnt[dst], 1);
            if (slot < CAP) {
                csrp[dst * CAP + slot] = src;
            } else {                              // rare (P(deg>32) ~ 1e-4)
                int o = atomicAdd(ovfcnt, 1);
                ovf[2 * o] = src;
                ovf[2 * o + 1] = dst;
            }
        }
    }
}

// ---------- per-node separable Gaussian factors (isd from cnt) ----------
__global__ void k_AB(const int* __restrict__ cnt, const float* __restrict__ mu,
                     const float* __restrict__ sigma,
                     float4* __restrict__ A4, float4* __restrict__ B4, int n) {
    int i = blockIdx.x * 256 + threadIdx.x;
    if (i >= n) return;
    int c = cnt[i];
    float v = rsqrtf((float)(c > 1 ? c : 1));
    float a[4], b[4];
    #pragma unroll
    for (int k = 0; k < 4; ++k) {
        float s0 = sigma[2 * k], s1 = sigma[2 * k + 1];
        float w0 = -0.5f / (EPS + s0 * s0);
        float w1 = -0.5f / (EPS + s1 * s1);
        float d0 = v - mu[2 * k];
        float d1 = v - mu[2 * k + 1];
        a[k] = __expf(d0 * d0 * w0);
        b[k] = __expf(d1 * d1 * w1);
    }
    A4[i] = (float4){a[0], a[1], a[2], a[3]};
    B4[i] = (float4){b[0], b[1], b[2], b[3]};
}

// ---------- pack combined B = [B_g ; root] (320x64) into MFMA fragment order ----------
__global__ void k_packB(const float* __restrict__ g, const float* __restrict__ root,
                        unsigned short* __restrict__ Bhi, unsigned short* __restrict__ Blo) {
    int idx = blockIdx.x * 256 + threadIdx.x;      // 0..20479
    if (idx >= 20480) return;
    int i  = idx & 7;
    int l  = (idx >> 3) & 63;
    int ct = idx >> 9;                              // c*4 + t
    int c = ct >> 2, t = ct & 3;
    int kk = c * 32 + ((l >> 4) & 3) * 8 + i;
    int j  = t * 16 + (l & 15);
    float v = (kk < 256) ? g[(kk & 63) * 256 + (kk >> 6) * 64 + j]
                         : root[(kk - 256) * 64 + j];
    unsigned short hi = f2bf(v);
    unsigned short lo = f2bf(v - bf2f(hi));
    Bhi[idx] = hi;
    Blo[idx] = lo;
}

// ---------- fused gather + MFMA transform ----------
// Phase 1: 4 waves gather 4 nodes each; h values split to bf16 hi/lo AT WRITE
// (identical conversion as before, moved earlier -> bit-identical output, and
// phase 2 reads MFMA fragments straight from LDS with no VALU conversion).
__global__ __launch_bounds__(256, 8) void k_fused(
    const int* __restrict__ cnt, const int* __restrict__ csrp,
    const int* __restrict__ ovf, const int* __restrict__ ovfcnt,
    const float4* __restrict__ A4, const float4* __restrict__ B4,
    const float* __restrict__ x,
    const unsigned short* __restrict__ Bhi, const unsigned short* __restrict__ Blo,
    const float* __restrict__ bias, float* __restrict__ out, int n) {
    __shared__ unsigned short hsH[16 * HS2];
    __shared__ unsigned short hsL[16 * HS2];
    const int lane = threadIdx.x & 63;
    const int w    = threadIdx.x >> 6;             // 0..3
    const int r0   = blockIdx.x * 16;

    // ---- phase 1: gather 4 nodes per wave ----
    for (int q = 0; q < 4; ++q) {
        const int nd   = w * 4 + q;
        const int node = r0 + nd;
        float a0 = 0.f, a1 = 0.f, a2 = 0.f, a3 = 0.f;
        float sc0 = 0.f, sc1 = 0.f, sc2 = 0.f, sc3 = 0.f;
        if (node < n) {
            const int len = cnt[node];
            const int m   = len < CAP ? len : CAP;
            const int* cp = csrp + (size_t)node * CAP;
            if (m > 0) {                            // depth-2 pipelined edge loop
                int    s_cur  = cp[0];
                float4 A_cur  = A4[s_cur];
                float  xv_cur = x[(size_t)s_cur * 64 + lane];
                int    s_nxt  = (m > 1) ? cp[1] : s_cur;
                for (int j = 0; j < m; ++j) {
                    int    s_n2 = (j + 2 < m) ? cp[j + 2] : s_nxt;
                    float4 A_n  = A4[s_nxt];
                    float  xv_n = x[(size_t)s_nxt * 64 + lane];
                    a0 = fmaf(A_cur.x, xv_cur, a0);
                    a1 = fmaf(A_cur.y, xv_cur, a1);
                    a2 = fmaf(A_cur.z, xv_cur, a2);
                    a3 = fmaf(A_cur.w, xv_cur, a3);
                    A_cur = A_n; xv_cur = xv_n; s_nxt = s_n2;
                }
            }
            if (len > CAP) {                        // rare overflow path
                const int no = *ovfcnt;
                for (int j = 0; j < no; ++j) {
                    int od = ovf[2 * j + 1];
                    if (od == node) {
                        int os = ovf[2 * j];
                        float4 Av = A4[os];
                        float  xv = x[(size_t)os * 64 + lane];
                        a0 = fmaf(Av.x, xv, a0);
                        a1 = fmaf(Av.y, xv, a1);
                        a2 = fmaf(Av.z, xv, a2);
                        a3 = fmaf(Av.w, xv, a3);
                    }
                }
            }
            const float invd = 1.0f / (float)(len > 1 ? len : 1);
            float4 Bv = B4[node];
            sc0 = Bv.x * invd; sc1 = Bv.y * invd;
            sc2 = Bv.z * invd; sc3 = Bv.w * invd;
        }
        float v0 = a0 * sc0, v1 = a1 * sc1, v2 = a2 * sc2, v3 = a3 * sc3;
        const int hb = nd * HS2;
        unsigned short u0 = f2bf(v0), u1 = f2bf(v1), u2 = f2bf(v2), u3 = f2bf(v3);
        hsH[hb + lane]       = u0;  hsL[hb + lane]       = f2bf(v0 - bf2f(u0));
        hsH[hb + 64 + lane]  = u1;  hsL[hb + 64 + lane]  = f2bf(v1 - bf2f(u1));
        hsH[hb + 128 + lane] = u2;  hsL[hb + 128 + lane] = f2bf(v2 - bf2f(u2));
        hsH[hb + 192 + lane] = u3;  hsL[hb + 192 + lane] = f2bf(v3 - bf2f(u3));
    }
    __syncthreads();

    // ---- phase 2: wave w computes col-tile t = w ----
    const int t     = w;
    const int arow  = r0 + (lane & 15);
    const int arowc = arow < n ? arow : n - 1;
    const int kgrp  = (lane >> 4) * 8;
    f32x4 acc = (f32x4){0.f, 0.f, 0.f, 0.f};

    #pragma unroll
    for (int c = 0; c < 10; ++c) {
        short8 ahi, alo;
        if (c < 8) {
            const int off = (lane & 15) * HS2 + c * 32 + kgrp;
            ahi = *reinterpret_cast<const short8*>(&hsH[off]);
            alo = *reinterpret_cast<const short8*>(&hsL[off]);
        } else {
            const float* ap = x + (size_t)arowc * 64 + (c - 8) * 32 + kgrp;
            float4 p0 = *reinterpret_cast<const float4*>(ap);
            float4 p1 = *reinterpret_cast<const float4*>(ap + 4);
            float av[8] = {p0.x, p0.y, p0.z, p0.w, p1.x, p1.y, p1.z, p1.w};
            #pragma unroll
            for (int i = 0; i < 8; ++i) {
                unsigned short hi = f2bf(av[i]);
                ahi[i] = (short)hi;
                alo[i] = (short)f2bf(av[i] - bf2f(hi));
            }
        }
        const int boff = ((c * 4 + t) * 64 + lane) * 8;
        short8 bhi = *reinterpret_cast<const short8*>(Bhi + boff);
        short8 blo = *reinterpret_cast<const short8*>(Blo + boff);
        acc = __builtin_amdgcn_mfma_f32_16x16x32_bf16(ahi, bhi, acc, 0, 0, 0);
        acc = __builtin_amdgcn_mfma_f32_16x16x32_bf16(alo, bhi, acc, 0, 0, 0);
        acc = __builtin_amdgcn_mfma_f32_16x16x32_bf16(ahi, blo, acc, 0, 0, 0);
    }

    const int lq  = (lane >> 4) * 4;
    const int col = t * 16 + (lane & 15);
    const float bv = bias[col];
    #pragma unroll
    for (int q = 0; q < 4; ++q) {
        const int row = r0 + lq + q;
        if (row < n) {
            const size_t o = (size_t)row * 64 + col;
            float xres = x[o];
            float conv = acc[q] + bv;
            out[o] = xres + (conv > 0.f ? conv : 0.f);
        }
    }
}

extern "C" void kernel_launch(void* const* d_in, const int* in_sizes, int n_in,
                              void* d_out, int out_size, void* d_ws, size_t ws_size,
                              hipStream_t stream) {
    const float* x     = (const float*)d_in[0];
    const int*   ei    = (const int*)d_in[1];
    const float* g     = (const float*)d_in[2];
    const float* mu    = (const float*)d_in[3];
    const float* sigma = (const float*)d_in[4];
    const float* root  = (const float*)d_in[5];
    const float* bias  = (const float*)d_in[6];
    float* out = (float*)d_out;

    const int n = in_sizes[0] / 64;   // 100000
    const int E = in_sizes[1] / 2;    // 1600000

    // ws layout (4B units):
    //   cnt[n] | ovfcnt[4] | Bhi 10240 | Blo 10240 | A4 4n | B4 4n | csrp 32n | ovf 2E
    // Total ≈ 29.3 MB.
    int* cnt    = (int*)d_ws;
    int* ovfcnt = cnt + n;
    unsigned short* Bhi = (unsigned short*)(ovfcnt + 4);    // 20480 ushort
    unsigned short* Blo = Bhi + 20480;
    float4* A4  = (float4*)(Blo + 20480);
    float4* B4  = A4 + n;
    int* csrp   = (int*)(B4 + n);
    int* ovf    = csrp + (size_t)n * CAP;

    hipMemsetAsync(cnt, 0, (size_t)n * sizeof(int), stream);
    hipMemsetAsync(ovfcnt, 0, 4 * sizeof(int), stream);

    const int chunk = (n + NP - 1) / NP;
    for (int p = 0; p < NP; ++p) {
        int dlo = p * chunk;
        int dhi = dlo + chunk < n ? dlo + chunk : n;
        k_fill2<<<(E + 255) / 256, 256, 0, stream>>>(ei, E, dlo, dhi, cnt, csrp, ovf, ovfcnt);
    }
    k_AB<<<(n + 255) / 256, 256, 0, stream>>>(cnt, mu, sigma, A4, B4, n);
    k_packB<<<80, 256, 0, stream>>>(g, root, Bhi, Blo);
    const int nstrip = (n + 15) / 16;
    k_fused<<<nstrip, 256, 0, stream>>>(cnt, csrp, ovf, ovfcnt, A4, B4, x,
                                        Bhi, Blo, bias, out, n);
}